// Round 16
// baseline (415.340 us; speedup 1.0000x reference)
//
#include <hip/hip_runtime.h>

// SinkhornAttention on MI355X — MFMA f16, XCD swizzle, scaling-vector sinkhorn,
// and REASSOCIATED output path: out = W @ (value @ wo^T) + bo. This kills the
// V-transpose pass and the big outproj GEMM's dependency chain:
//   vproj: VW = value_flat @ woh^T   (value in native layout, 68.7 GF)
//   fin  : out[b,j] = W_b @ VW[k*128+j*8+b rows] + bo   (17 GF, BW-bound)
// T=S=4096, B=8, E=1024, BUCKET=16 -> nb=nkb=256. TAU=0.75, ITERS=8, SCALE=1/32.
// d_out = [ out | attn_weights | log_alpha ] f32.
// Noise (verified r7): threefry2x32 partitionable, counts (0,i), draw = o0 ^ o1.

typedef float    f32x4 __attribute__((ext_vector_type(4)));
typedef _Float16 h4    __attribute__((ext_vector_type(4)));
typedef _Float16 h8    __attribute__((ext_vector_type(8)));

#define OUT_ELEMS 33554432
#define AW_ELEMS  524288

__device__ __forceinline__ void gload16(const void* g, void* l) {
  __builtin_amdgcn_global_load_lds((__attribute__((address_space(1))) void*)g,
                                   (__attribute__((address_space(3))) void*)l,
                                   16, 0, 0);
}

// ---------------- weight conversion f32 -> f16 -------------------------------
__global__ __launch_bounds__(256) void convw_k(const float* __restrict__ wq,
                                               const float* __restrict__ wk,
                                               const float* __restrict__ wo,
                                               _Float16* __restrict__ dst) {
  int which = blockIdx.y;
  const float* src = which == 0 ? wq : (which == 1 ? wk : wo);
  size_t idx = (size_t)blockIdx.x * 256 + threadIdx.x;
  f32x4 v = ((const f32x4*)src)[idx];
  ((h4*)(dst + (size_t)which * 1048576))[idx] = __builtin_convertvector(v, h4);
}

// ---------------- bucket mean over T (stride B*E), f32 -> f16 ----------------
__global__ __launch_bounds__(256) void bucket_k(const float* __restrict__ q,
                                                const float* __restrict__ k,
                                                _Float16* __restrict__ qbar,
                                                _Float16* __restrict__ kbar) {
  const float* src = blockIdx.y ? k : q;
  _Float16* dst = blockIdx.y ? kbar : qbar;
  unsigned t = blockIdx.x * 256 + threadIdx.x;                    // 0..524287
  int e4 = t & 255, i = (t >> 8) & 255, b = t >> 16;
  const f32x4* p = (const f32x4*)(src + ((size_t)(i * 16) * 8 + b) * 1024) + e4;
  f32x4 acc = {0.f, 0.f, 0.f, 0.f};
  #pragma unroll
  for (int j = 0; j < 16; ++j) acc += p[j * 2048];
  acc *= 0.0625f;
  ((h4*)(dst + (size_t)(b * 256 + i) * 1024))[e4] = __builtin_convertvector(acc, h4);
}

// ---------------- JAX threefry2x32 gumbel (verified r7) ----------------------
// Writes EXP-DOMAIN entries: e = exp((logits + g)/tau) (validated r12-r15).
__device__ __forceinline__ unsigned rotl32(unsigned x, int r) {
  return (x << r) | (x >> (32 - r));
}
__global__ __launch_bounds__(256) void gumbel_k(const float* __restrict__ logits,
                                                float* __restrict__ ebuf) {
  unsigned i = blockIdx.x * 256 + threadIdx.x;                    // 0..524287
  const unsigned k0 = 0u, k1 = 42u, k2 = 0u ^ 42u ^ 0x1BD11BDAu;
  unsigned x0 = 0u + k0, x1 = i + k1;                             // counts (hi,lo)=(0,i)
#define R4(a,b,c,d) \
  x0 += x1; x1 = rotl32(x1, a); x1 ^= x0; \
  x0 += x1; x1 = rotl32(x1, b); x1 ^= x0; \
  x0 += x1; x1 = rotl32(x1, c); x1 ^= x0; \
  x0 += x1; x1 = rotl32(x1, d); x1 ^= x0;
  R4(13,15,26,6)  x0 += k1; x1 += k2 + 1u;
  R4(17,29,16,24) x0 += k2; x1 += k0 + 2u;
  R4(13,15,26,6)  x0 += k0; x1 += k1 + 3u;
  R4(17,29,16,24) x0 += k1; x1 += k2 + 4u;
  R4(13,15,26,6)  x0 += k2; x1 += k0 + 5u;
#undef R4
  unsigned bits = x0 ^ x1;
  float u = __builtin_bit_cast(float, (bits >> 9) | 0x3f800000u) - 1.0f;
  float g = -logf(-logf(u + 1e-6f) + 1e-6f);
  ebuf[i] = __expf((logits[i] + g) / 0.75f);
}

// ---------------- Sinkhorn via scaling vectors: 1 block/batch (r15, works) ---
__global__ __launch_bounds__(1024) void sink_rc_k(const float* __restrict__ ein,
                                                  float* __restrict__ attnw,
                                                  _Float16* __restrict__ wsh) {
  const int b = blockIdx.x;
  const int t = threadIdx.x;
  const int r = t >> 2, p = t & 3;       // row-sweep role
  const int k = t & 255, g = t >> 8;     // col-sweep role
  const float* Eb = ein + (size_t)b * 65536;
  const f32x4* Eb4 = (const f32x4*)Eb;

  __shared__ float ra[256];
  __shared__ float cb[256];
  __shared__ float part[4][256];
  if (t < 256) cb[t] = 1.0f;
  __syncthreads();

  const f32x4* cb4 = (const f32x4*)cb;

  for (int it = 0; it < 8; ++it) {
    float s = 0.f;
    #pragma unroll
    for (int i = 0; i < 16; ++i) {
      f32x4 e = Eb4[r * 64 + p * 16 + i];
      f32x4 c = cb4[p * 16 + i];
      f32x4 m = e * c;
      s += (m[0] + m[1]) + (m[2] + m[3]);
    }
    s += __shfl_xor(s, 1, 64);
    s += __shfl_xor(s, 2, 64);
    if (p == 0) ra[r] = 1.0f / s;
    __syncthreads();
    float s2 = 0.f;
    #pragma unroll 8
    for (int q2 = 0; q2 < 64; ++q2) {
      int row = g * 64 + q2;
      s2 += Eb[row * 256 + k] * ra[row];
    }
    part[g][k] = s2;
    __syncthreads();
    if (t < 256) {
      cb[t] = 1.0f / (part[0][t] + part[1][t] + part[2][t] + part[3][t]);
    }
    __syncthreads();
  }

  const float arow = ra[r];
  f32x4* aw = (f32x4*)(attnw + (size_t)b * 65536 + r * 256 + p * 64);
  h4* wh = (h4*)(wsh + (size_t)b * 65536 + r * 256 + p * 64);
  #pragma unroll
  for (int i = 0; i < 16; ++i) {
    f32x4 e = Eb4[r * 64 + p * 16 + i];
    f32x4 c = cb4[p * 16 + i];
    f32x4 w = e * c * arow;
    aw[i] = w;
    h4 hv;
    hv[0] = (_Float16)w[0]; hv[1] = (_Float16)w[1];
    hv[2] = (_Float16)w[2]; hv[3] = (_Float16)w[3];
    wh[i] = hv;
  }
}

// ---------------- generic 128x128 NT MFMA GEMM (m97 structure) ---------------
// MODE 0: proj   (1-D grid 128, XCD-chunked) -> f16 out + bias
// MODE 1: logits (3-D grid)                  -> f32 /32 to log_alpha
template <int MODE>
__global__ __launch_bounds__(256) void gemm128(const _Float16* __restrict__ A,
                                               const _Float16* __restrict__ B,
                                               const float* __restrict__ bias,
                                               void* __restrict__ out0,
                                               int K, int lda, int ldb) {
  const int tid = threadIdx.x, lane = tid & 63, w = tid >> 6;
  int bx = blockIdx.x, by = blockIdx.y, bz = blockIdx.z;
  if constexpr (MODE == 0) {
    int wid = ((bx & 7) << 4) + (bx >> 3);
    by = wid & 7; bx = wid >> 3;
  }
  const int m0 = bx * 128, n0 = by * 128;
  const _Float16* Ab = A;
  const _Float16* Bb = B;
  if constexpr (MODE == 1) { Ab += (size_t)bz * 262144; Bb += (size_t)bz * 262144; }
  __shared__ _Float16 lA[128 * 32];
  __shared__ _Float16 lB[128 * 32];
  f32x4 acc[4][4] = {};
  const int wm = (w >> 1) * 64, wn = (w & 1) * 64;
  const int fr = lane & 15, fk = (lane >> 4) * 8;
  const int q0 = tid, q1 = tid + 256;

  for (int kt = 0; kt < K; kt += 32) {
    __syncthreads();
    gload16(Ab + (size_t)(m0 + (q0 >> 2)) * lda + kt + (q0 & 3) * 8, &lA[(w * 64) * 8]);
    gload16(Ab + (size_t)(m0 + (q1 >> 2)) * lda + kt + (q1 & 3) * 8, &lA[(256 + w * 64) * 8]);
    gload16(Bb + (size_t)(n0 + (q0 >> 2)) * ldb + kt + (q0 & 3) * 8, &lB[(w * 64) * 8]);
    gload16(Bb + (size_t)(n0 + (q1 >> 2)) * ldb + kt + (q1 & 3) * 8, &lB[(256 + w * 64) * 8]);
    __syncthreads();
    h8 af[4], bf[4];
    #pragma unroll
    for (int i = 0; i < 4; ++i) {
      af[i] = *(const h8*)&lA[(wm + i * 16 + fr) * 32 + fk];
      bf[i] = *(const h8*)&lB[(wn + i * 16 + fr) * 32 + fk];
    }
    #pragma unroll
    for (int mi = 0; mi < 4; ++mi)
      #pragma unroll
      for (int ni = 0; ni < 4; ++ni)
        acc[mi][ni] = __builtin_amdgcn_mfma_f32_16x16x32_f16(af[mi], bf[ni], acc[mi][ni], 0, 0, 0);
  }

  const int er = (lane >> 4) * 4;
  #pragma unroll
  for (int mi = 0; mi < 4; ++mi) {
    #pragma unroll
    for (int ni = 0; ni < 4; ++ni) {
      #pragma unroll
      for (int r = 0; r < 4; ++r) {
        int row = m0 + wm + mi * 16 + er + r;
        int col = n0 + wn + ni * 16 + fr;
        float val = acc[mi][ni][r];
        if constexpr (MODE == 0) {
          ((_Float16*)out0)[(size_t)row * 1024 + col] = (_Float16)(val + bias[col]);
        } else {
          ((float*)out0)[(size_t)bz * 65536 + row * 256 + col] = val * 0.03125f;
        }
      }
    }
  }
}

// ---------------- vproj: VW[m][f] = sum_e value[m][e] * woh[f][e] ------------
// M=32768 (native value rows), N=1024, K=1024. A: f32 reg-staged -> f16 LDS.
// Grid 2048, XCD-chunked (n fastest within chunk for value-panel L2 sharing).
__global__ __launch_bounds__(256) void vproj_k(const float* __restrict__ V,
                                               const _Float16* __restrict__ woh,
                                               _Float16* __restrict__ VW) {
  const int tid = threadIdx.x, lane = tid & 63, w = tid >> 6;
  int bx = blockIdx.x;
  int wid = ((bx & 7) << 8) + (bx >> 3);
  const int m0 = (wid >> 3) * 128, n0 = (wid & 7) * 128;
  __shared__ _Float16 lA[128 * 32];
  __shared__ _Float16 lB[128 * 32];
  f32x4 acc[4][4] = {};
  const int wm = (w >> 1) * 64, wn = (w & 1) * 64;
  const int fr = lane & 15, fk = (lane >> 4) * 8;
  const int q0 = tid, q1 = tid + 256;
  const int ar = tid >> 3, ae = (tid & 7) * 4;

  for (int kt = 0; kt < 1024; kt += 32) {
    __syncthreads();
    #pragma unroll
    for (int p = 0; p < 4; ++p) {
      int row = p * 32 + ar;
      f32x4 x = *(const f32x4*)(V + (size_t)(m0 + row) * 1024 + kt + ae);
      *(h4*)&lA[row * 32 + ae] = __builtin_convertvector(x, h4);
    }
    gload16(woh + (size_t)(n0 + (q0 >> 2)) * 1024 + kt + (q0 & 3) * 8, &lB[(w * 64) * 8]);
    gload16(woh + (size_t)(n0 + (q1 >> 2)) * 1024 + kt + (q1 & 3) * 8, &lB[(256 + w * 64) * 8]);
    __syncthreads();
    h8 af[4], bf[4];
    #pragma unroll
    for (int i = 0; i < 4; ++i) {
      af[i] = *(const h8*)&lA[(wm + i * 16 + fr) * 32 + fk];
      bf[i] = *(const h8*)&lB[(wn + i * 16 + fr) * 32 + fk];
    }
    #pragma unroll
    for (int mi = 0; mi < 4; ++mi)
      #pragma unroll
      for (int ni = 0; ni < 4; ++ni)
        acc[mi][ni] = __builtin_amdgcn_mfma_f32_16x16x32_f16(af[mi], bf[ni], acc[mi][ni], 0, 0, 0);
  }

  const int er = (lane >> 4) * 4;
  #pragma unroll
  for (int mi = 0; mi < 4; ++mi)
    #pragma unroll
    for (int ni = 0; ni < 4; ++ni)
      #pragma unroll
      for (int r = 0; r < 4; ++r) {
        int row = m0 + wm + mi * 16 + er + r;
        int col = n0 + wn + ni * 16 + fr;
        VW[(size_t)row * 1024 + col] = (_Float16)acc[mi][ni][r];
      }
}

// ---------------- fin: out[b,j] = W_b @ VW[k*128+j*8+b] + bo -----------------
// Per (b,j): M=256 (q), N=1024 (f), K=256 (k). A=wsh (k-contig, gload_lds).
// B rows are k-strided in VW (f-contiguous) -> reg-stage + LDS transpose to
// lB[f][k] (stride 40 f16: 80 B rows keep h8 frag reads 16B-aligned).
__global__ __launch_bounds__(256) void fin_k(const _Float16* __restrict__ wsh,
                                             const _Float16* __restrict__ VW,
                                             const float* __restrict__ bo,
                                             float* __restrict__ out) {
  const int tid = threadIdx.x, lane = tid & 63, w = tid >> 6;
  int bx = blockIdx.x;
  int wid = ((bx & 7) << 8) + (bx >> 3);
  const int bj = wid >> 4, mt = (wid >> 3) & 1, nt = wid & 7;
  const int b = bj & 7, j = bj >> 3;
  const int m0 = mt * 128, n0 = nt * 128;
  const _Float16* Ab = wsh + (size_t)b * 65536;
  __shared__ _Float16 lA[128 * 32];
  __shared__ _Float16 lB[128 * 40];
  f32x4 acc[4][4] = {};
  const int wm = (w >> 1) * 64, wn = (w & 1) * 64;
  const int fr = lane & 15, fk = (lane >> 4) * 8;
  const int q0 = tid, q1 = tid + 256;
  const int bk = tid >> 3, bf0 = (tid & 7) * 8;

  for (int kt = 0; kt < 256; kt += 32) {
    __syncthreads();
    gload16(Ab + (size_t)(m0 + (q0 >> 2)) * 256 + kt + (q0 & 3) * 8, &lA[(w * 64) * 8]);
    gload16(Ab + (size_t)(m0 + (q1 >> 2)) * 256 + kt + (q1 & 3) * 8, &lA[(256 + w * 64) * 8]);
    #pragma unroll
    for (int half = 0; half < 2; ++half) {
      int f0 = bf0 + half * 64;
      int vrow = (kt + bk) * 128 + j * 8 + b;          // VW row for this k
      h8 v = *(const h8*)(VW + (size_t)vrow * 1024 + n0 + f0);
      #pragma unroll
      for (int u = 0; u < 8; ++u) lB[(f0 + u) * 40 + bk] = v[u];
    }
    __syncthreads();
    h8 af[4], bfv[4];
    #pragma unroll
    for (int i = 0; i < 4; ++i) {
      af[i] = *(const h8*)&lA[(wm + i * 16 + fr) * 32 + fk];
      bfv[i] = *(const h8*)&lB[(wn + i * 16 + fr) * 40 + fk];
    }
    #pragma unroll
    for (int mi = 0; mi < 4; ++mi)
      #pragma unroll
      for (int ni = 0; ni < 4; ++ni)
        acc[mi][ni] = __builtin_amdgcn_mfma_f32_16x16x32_f16(af[mi], bfv[ni], acc[mi][ni], 0, 0, 0);
  }

  const int er = (lane >> 4) * 4;
  #pragma unroll
  for (int mi = 0; mi < 4; ++mi)
    #pragma unroll
    for (int ni = 0; ni < 4; ++ni)
      #pragma unroll
      for (int r = 0; r < 4; ++r) {
        int row = m0 + wm + mi * 16 + er + r;          // q
        int col = n0 + wn + ni * 16 + fr;              // f
        out[((size_t)(row * 16 + j) * 8 + b) * 1024 + col] = acc[mi][ni][r] + bo[col];
      }
}

// -----------------------------------------------------------------------------
extern "C" void kernel_launch(void* const* d_in, const int* in_sizes, int n_in,
                              void* d_out, int out_size, void* d_ws, size_t ws_size,
                              hipStream_t stream) {
  const float* query = (const float*)d_in[0];
  const float* key   = (const float*)d_in[1];
  const float* value = (const float*)d_in[2];
  const float* wq    = (const float*)d_in[3];
  const float* bq    = (const float*)d_in[4];
  const float* wk    = (const float*)d_in[5];
  const float* bk    = (const float*)d_in[6];
  const float* wo    = (const float*)d_in[7];
  const float* bo    = (const float*)d_in[8];

  float* out      = (float*)d_out;
  float* attnw    = out + OUT_ELEMS;            // 8*256*256
  float* logalpha = out + OUT_ELEMS + AW_ELEMS; // logits (pre-noise)

  char* ws = (char*)d_ws;
  const size_t MB = 1024 * 1024;
  _Float16* wqh   = (_Float16*)(ws + 0 * MB);   // 2 MB
  _Float16* wkh   = (_Float16*)(ws + 2 * MB);   // 2 MB
  _Float16* woh   = (_Float16*)(ws + 4 * MB);   // 2 MB
  _Float16* qbar  = (_Float16*)(ws + 6 * MB);   // 4 MB  (2048x1024)
  _Float16* kbar  = (_Float16*)(ws + 10 * MB);  // 4 MB
  _Float16* qbh   = (_Float16*)(ws + 14 * MB);  // 4 MB
  _Float16* kbh   = (_Float16*)(ws + 18 * MB);  // 4 MB
  float*    ebuf  = (float*)(ws + 22 * MB);     // 2 MB  exp-domain entries
  _Float16* wsh   = (_Float16*)(ws + 25 * MB);  // 1 MB  attn weights f16
  _Float16* VW    = (_Float16*)(ws + 26 * MB);  // 64 MB value @ wo^T, f16
  (void)in_sizes; (void)n_in; (void)out_size; (void)ws_size;

  convw_k<<<dim3(1024, 3), 256, 0, stream>>>(wq, wk, wo, wqh);
  bucket_k<<<dim3(2048, 2), 256, 0, stream>>>(query, key, qbar, kbar);

  vproj_k<<<dim3(2048), 256, 0, stream>>>(value, woh, VW);

  gemm128<0><<<dim3(128), 256, 0, stream>>>(qbar, wqh, bq, qbh, 1024, 1024, 1024);
  gemm128<0><<<dim3(128), 256, 0, stream>>>(kbar, wkh, bk, kbh, 1024, 1024, 1024);
  gemm128<1><<<dim3(2, 2, 8), 256, 0, stream>>>(qbh, kbh, nullptr, logalpha, 1024, 1024, 1024);

  gumbel_k<<<dim3(2048), 256, 0, stream>>>(logalpha, ebuf);
  sink_rc_k<<<dim3(8), 1024, 0, stream>>>(ebuf, attnw, wsh);

  fin_k<<<dim3(2048), 256, 0, stream>>>(wsh, VW, bo, out);
}

// Round 17
// 377.883 us; speedup vs baseline: 1.0991x; 1.0991x over previous
//
#include <hip/hip_runtime.h>

// SinkhornAttention on MI355X — r15 pipeline (best known: 400us) + merged
// q/k projection launch (256 blocks, full CU coverage).
// r16 lesson: reassociated out = W@(V@wo^T) REGRESSED — f32 reg-staged A makes
// vproj 461 TF vs outproj's 625 TF; m97 staging needs gload_lds on BOTH operands.
// T=S=4096, B=8, E=1024, BUCKET=16 -> nb=nkb=256. TAU=0.75, ITERS=8, SCALE=1/32.
// d_out = [ out | attn_weights | log_alpha ] f32.
// Noise (verified r7): threefry2x32 partitionable, counts (0,i), draw = o0 ^ o1.

typedef float    f32x4 __attribute__((ext_vector_type(4)));
typedef _Float16 h4    __attribute__((ext_vector_type(4)));
typedef _Float16 h8    __attribute__((ext_vector_type(8)));

#define OUT_ELEMS 33554432
#define AW_ELEMS  524288

__device__ __forceinline__ void gload16(const void* g, void* l) {
  __builtin_amdgcn_global_load_lds((__attribute__((address_space(1))) void*)g,
                                   (__attribute__((address_space(3))) void*)l,
                                   16, 0, 0);
}

// ---------------- weight conversion f32 -> f16 -------------------------------
__global__ __launch_bounds__(256) void convw_k(const float* __restrict__ wq,
                                               const float* __restrict__ wk,
                                               const float* __restrict__ wo,
                                               _Float16* __restrict__ dst) {
  int which = blockIdx.y;
  const float* src = which == 0 ? wq : (which == 1 ? wk : wo);
  size_t idx = (size_t)blockIdx.x * 256 + threadIdx.x;
  f32x4 v = ((const f32x4*)src)[idx];
  ((h4*)(dst + (size_t)which * 1048576))[idx] = __builtin_convertvector(v, h4);
}

// ---------------- bucket mean over T (stride B*E), f32 -> f16 ----------------
__global__ __launch_bounds__(256) void bucket_k(const float* __restrict__ q,
                                                const float* __restrict__ k,
                                                _Float16* __restrict__ qbar,
                                                _Float16* __restrict__ kbar) {
  const float* src = blockIdx.y ? k : q;
  _Float16* dst = blockIdx.y ? kbar : qbar;
  unsigned t = blockIdx.x * 256 + threadIdx.x;                    // 0..524287
  int e4 = t & 255, i = (t >> 8) & 255, b = t >> 16;
  const f32x4* p = (const f32x4*)(src + ((size_t)(i * 16) * 8 + b) * 1024) + e4;
  f32x4 acc = {0.f, 0.f, 0.f, 0.f};
  #pragma unroll
  for (int j = 0; j < 16; ++j) acc += p[j * 2048];
  acc *= 0.0625f;
  ((h4*)(dst + (size_t)(b * 256 + i) * 1024))[e4] = __builtin_convertvector(acc, h4);
}

// ---------------- V transpose: vt[b][j][e][k] = v[(k*16+j)][b][e], f32->f16 --
__global__ __launch_bounds__(256) void vtrans_k(const float* __restrict__ v,
                                                _Float16* __restrict__ vt) {
  int bid = blockIdx.x;
  int kb = bid & 3, eb = (bid >> 2) & 15, j = (bid >> 6) & 15, b = bid >> 10;
  int k0 = kb * 64, e0 = eb * 64;
  __shared__ _Float16 tile[64][72];
  int t = threadIdx.x, r = t >> 2, qq = t & 3;
  const float* src = v + ((size_t)((k0 + r) * 16 + j) * 8 + b) * 1024 + e0;
  #pragma unroll
  for (int ii = 0; ii < 4; ++ii) {
    f32x4 x = ((const f32x4*)src)[qq + ii * 4];
    *(h4*)&tile[r][(qq + ii * 4) * 4] = __builtin_convertvector(x, h4);
  }
  __syncthreads();
  _Float16* dstp = vt + (((size_t)(b * 16 + j) * 1024 + e0 + r) * 256 + k0 + qq * 16);
  h8 o0, o1;
  #pragma unroll
  for (int kk = 0; kk < 8; ++kk) o0[kk] = tile[qq * 16 + kk][r];
  #pragma unroll
  for (int kk = 0; kk < 8; ++kk) o1[kk] = tile[qq * 16 + 8 + kk][r];
  *(h8*)dstp = o0;
  *(h8*)(dstp + 8) = o1;
}

// ---------------- JAX threefry2x32 gumbel (verified r7) ----------------------
// Writes EXP-DOMAIN entries: e = exp((logits + g)/tau) (validated r12-r16).
__device__ __forceinline__ unsigned rotl32(unsigned x, int r) {
  return (x << r) | (x >> (32 - r));
}
__global__ __launch_bounds__(256) void gumbel_k(const float* __restrict__ logits,
                                                float* __restrict__ ebuf) {
  unsigned i = blockIdx.x * 256 + threadIdx.x;                    // 0..524287
  const unsigned k0 = 0u, k1 = 42u, k2 = 0u ^ 42u ^ 0x1BD11BDAu;
  unsigned x0 = 0u + k0, x1 = i + k1;                             // counts (hi,lo)=(0,i)
#define R4(a,b,c,d) \
  x0 += x1; x1 = rotl32(x1, a); x1 ^= x0; \
  x0 += x1; x1 = rotl32(x1, b); x1 ^= x0; \
  x0 += x1; x1 = rotl32(x1, c); x1 ^= x0; \
  x0 += x1; x1 = rotl32(x1, d); x1 ^= x0;
  R4(13,15,26,6)  x0 += k1; x1 += k2 + 1u;
  R4(17,29,16,24) x0 += k2; x1 += k0 + 2u;
  R4(13,15,26,6)  x0 += k0; x1 += k1 + 3u;
  R4(17,29,16,24) x0 += k1; x1 += k2 + 4u;
  R4(13,15,26,6)  x0 += k2; x1 += k0 + 5u;
#undef R4
  unsigned bits = x0 ^ x1;
  float u = __builtin_bit_cast(float, (bits >> 9) | 0x3f800000u) - 1.0f;
  float g = -logf(-logf(u + 1e-6f) + 1e-6f);
  ebuf[i] = __expf((logits[i] + g) / 0.75f);
}

// ---------------- Sinkhorn via scaling vectors: 1 block/batch (r15) ----------
__global__ __launch_bounds__(1024) void sink_rc_k(const float* __restrict__ ein,
                                                  float* __restrict__ attnw,
                                                  _Float16* __restrict__ wsh) {
  const int b = blockIdx.x;
  const int t = threadIdx.x;
  const int r = t >> 2, p = t & 3;       // row-sweep role
  const int k = t & 255, g = t >> 8;     // col-sweep role
  const float* Eb = ein + (size_t)b * 65536;
  const f32x4* Eb4 = (const f32x4*)Eb;

  __shared__ float ra[256];
  __shared__ float cb[256];
  __shared__ float part[4][256];
  if (t < 256) cb[t] = 1.0f;
  __syncthreads();

  const f32x4* cb4 = (const f32x4*)cb;

  for (int it = 0; it < 8; ++it) {
    float s = 0.f;
    #pragma unroll
    for (int i = 0; i < 16; ++i) {
      f32x4 e = Eb4[r * 64 + p * 16 + i];
      f32x4 c = cb4[p * 16 + i];
      f32x4 m = e * c;
      s += (m[0] + m[1]) + (m[2] + m[3]);
    }
    s += __shfl_xor(s, 1, 64);
    s += __shfl_xor(s, 2, 64);
    if (p == 0) ra[r] = 1.0f / s;
    __syncthreads();
    float s2 = 0.f;
    #pragma unroll 8
    for (int q2 = 0; q2 < 64; ++q2) {
      int row = g * 64 + q2;
      s2 += Eb[row * 256 + k] * ra[row];
    }
    part[g][k] = s2;
    __syncthreads();
    if (t < 256) {
      cb[t] = 1.0f / (part[0][t] + part[1][t] + part[2][t] + part[3][t]);
    }
    __syncthreads();
  }

  const float arow = ra[r];
  f32x4* aw = (f32x4*)(attnw + (size_t)b * 65536 + r * 256 + p * 64);
  h4* wh = (h4*)(wsh + (size_t)b * 65536 + r * 256 + p * 64);
  #pragma unroll
  for (int i = 0; i < 16; ++i) {
    f32x4 e = Eb4[r * 64 + p * 16 + i];
    f32x4 c = cb4[p * 16 + i];
    f32x4 w = e * c * arow;
    aw[i] = w;
    h4 hv;
    hv[0] = (_Float16)w[0]; hv[1] = (_Float16)w[1];
    hv[2] = (_Float16)w[2]; hv[3] = (_Float16)w[3];
    wh[i] = hv;
  }
}

// ---------------- generic 128x128 NT MFMA GEMM (m97 structure) ---------------
// C[M,N] = A[M,K] @ B[N,K]^T ; A,B f16 K-contiguous. 256 thr, 4 waves, BK=32.
// MODE 0: proj (grid 128 x 1 x 2, z = q/k) -> f16 out + bias; A/B/out/bias
//         z-strided (qbar|kbar, wqh|wkh, qbh|kbh contiguous slabs).
// MODE 1: logits  (3-D grid)                   -> f32 /32 to log_alpha
// MODE 2: attn    (1-D grid 2048, XCD-chunked) -> f16 attnh
// MODE 3: outproj (1-D grid 2048, XCD-chunked) -> f32 out + bias
template <int MODE>
__global__ __launch_bounds__(256) void gemm128(const _Float16* __restrict__ A,
                                               const _Float16* __restrict__ B,
                                               const float* __restrict__ bias,
                                               const float* __restrict__ bias2,
                                               void* __restrict__ out0,
                                               int K, int lda, int ldb) {
  const int tid = threadIdx.x, lane = tid & 63, w = tid >> 6;
  int bx = blockIdx.x, by = blockIdx.y, bz = blockIdx.z;
  if constexpr (MODE == 0) {           // per-z grid 128: m=wid>>3 (16), n=wid&7
    int wid = ((bx & 7) << 4) + (bx >> 3);
    by = wid & 7; bx = wid >> 3;
  }
  if constexpr (MODE == 2) {           // grid 2048: x(2) fastest, y(8), z(128)
    int wid = ((bx & 7) << 8) + (bx >> 3);
    bz = wid >> 4; by = (wid >> 1) & 7; bx = wid & 1;
  }
  if constexpr (MODE == 3) {           // grid 2048: m=wid>>3 (256), n=wid&7
    int wid = ((bx & 7) << 8) + (bx >> 3);
    by = wid & 7; bx = wid >> 3;
  }
  const int m0 = bx * 128, n0 = by * 128;
  const _Float16* Ab = A;
  const _Float16* Bb = B;
  const float* bs = bias;
  if constexpr (MODE == 0) {
    Ab += (size_t)bz * 2097152;        // qbar -> kbar
    Bb += (size_t)bz * 1048576;        // wqh  -> wkh
    if (bz) bs = bias2;                // bq   -> bk
  }
  if constexpr (MODE == 1) { Ab += (size_t)bz * 262144; Bb += (size_t)bz * 262144; }
  if constexpr (MODE == 2) { Ab += (size_t)(bz >> 4) * 65536; Bb += (size_t)bz * 262144; }
  __shared__ _Float16 lA[128 * 32];
  __shared__ _Float16 lB[128 * 32];
  f32x4 acc[4][4] = {};
  const int wm = (w >> 1) * 64, wn = (w & 1) * 64;
  const int fr = lane & 15, fk = (lane >> 4) * 8;
  const int q0 = tid, q1 = tid + 256;

  for (int kt = 0; kt < K; kt += 32) {
    __syncthreads();
    gload16(Ab + (size_t)(m0 + (q0 >> 2)) * lda + kt + (q0 & 3) * 8, &lA[(w * 64) * 8]);
    gload16(Ab + (size_t)(m0 + (q1 >> 2)) * lda + kt + (q1 & 3) * 8, &lA[(256 + w * 64) * 8]);
    gload16(Bb + (size_t)(n0 + (q0 >> 2)) * ldb + kt + (q0 & 3) * 8, &lB[(w * 64) * 8]);
    gload16(Bb + (size_t)(n0 + (q1 >> 2)) * ldb + kt + (q1 & 3) * 8, &lB[(256 + w * 64) * 8]);
    __syncthreads();
    h8 af[4], bf[4];
    #pragma unroll
    for (int i = 0; i < 4; ++i) {
      af[i] = *(const h8*)&lA[(wm + i * 16 + fr) * 32 + fk];
      bf[i] = *(const h8*)&lB[(wn + i * 16 + fr) * 32 + fk];
    }
    #pragma unroll
    for (int mi = 0; mi < 4; ++mi)
      #pragma unroll
      for (int ni = 0; ni < 4; ++ni)
        acc[mi][ni] = __builtin_amdgcn_mfma_f32_16x16x32_f16(af[mi], bf[ni], acc[mi][ni], 0, 0, 0);
  }

  const int er = (lane >> 4) * 4;
  #pragma unroll
  for (int mi = 0; mi < 4; ++mi) {
    #pragma unroll
    for (int ni = 0; ni < 4; ++ni) {
      #pragma unroll
      for (int r = 0; r < 4; ++r) {
        int row = m0 + wm + mi * 16 + er + r;
        int col = n0 + wn + ni * 16 + fr;
        float val = acc[mi][ni][r];
        if constexpr (MODE == 0) {
          ((_Float16*)out0)[(size_t)bz * 2097152 + (size_t)row * 1024 + col] =
              (_Float16)(val + bs[col]);
        } else if constexpr (MODE == 1) {
          ((float*)out0)[(size_t)bz * 65536 + row * 256 + col] = val * 0.03125f;
        } else if constexpr (MODE == 2) {
          int b = bz >> 4, j = bz & 15;
          ((_Float16*)out0)[((size_t)(b * 4096 + row * 16 + j)) * 1024 + col] = (_Float16)val;
        } else {
          int bb = row >> 12, t = row & 4095;
          ((float*)out0)[((size_t)t * 8 + bb) * 1024 + col] = val + bs[col];
        }
      }
    }
  }
}

// -----------------------------------------------------------------------------
extern "C" void kernel_launch(void* const* d_in, const int* in_sizes, int n_in,
                              void* d_out, int out_size, void* d_ws, size_t ws_size,
                              hipStream_t stream) {
  const float* query = (const float*)d_in[0];
  const float* key   = (const float*)d_in[1];
  const float* value = (const float*)d_in[2];
  const float* wq    = (const float*)d_in[3];
  const float* bq    = (const float*)d_in[4];
  const float* wk    = (const float*)d_in[5];
  const float* bk    = (const float*)d_in[6];
  const float* wo    = (const float*)d_in[7];
  const float* bo    = (const float*)d_in[8];

  float* out      = (float*)d_out;
  float* attnw    = out + OUT_ELEMS;            // 8*256*256
  float* logalpha = out + OUT_ELEMS + AW_ELEMS; // logits (pre-noise)

  char* ws = (char*)d_ws;
  const size_t MB = 1024 * 1024;
  _Float16* wqh   = (_Float16*)(ws + 0 * MB);   // 2 MB  (wkh at +2MB, woh at +4MB)
  _Float16* woh   = (_Float16*)(ws + 4 * MB);   // 2 MB
  _Float16* qbar  = (_Float16*)(ws + 6 * MB);   // 4 MB  (2048x1024; kbar at +4MB)
  _Float16* kbar  = (_Float16*)(ws + 10 * MB);  // 4 MB
  _Float16* qbh   = (_Float16*)(ws + 14 * MB);  // 4 MB  (kbh at +4MB)
  _Float16* kbh   = (_Float16*)(ws + 18 * MB);  // 4 MB
  float*    ebuf  = (float*)(ws + 22 * MB);     // 2 MB  exp-domain entries
  _Float16* wsh   = (_Float16*)(ws + 25 * MB);  // 1 MB  attn weights f16
  _Float16* vt    = (_Float16*)(ws + 26 * MB);  // 64 MB vt[b][j][e][k]
  _Float16* attnh = (_Float16*)(ws + 90 * MB);  // 64 MB attn (B,T,E) f16
  (void)in_sizes; (void)n_in; (void)out_size; (void)ws_size;

  convw_k<<<dim3(1024, 3), 256, 0, stream>>>(wq, wk, wo, wqh);
  bucket_k<<<dim3(2048, 2), 256, 0, stream>>>(query, key, qbar, kbar);
  vtrans_k<<<dim3(8192), 256, 0, stream>>>(value, vt);

  // merged q/k projection: z=0 -> qbh = qbar@wqh^T + bq ; z=1 -> kbh (256 blocks)
  gemm128<0><<<dim3(128, 1, 2), 256, 0, stream>>>(qbar, wqh, bq, bk, qbh, 1024, 1024, 1024);
  gemm128<1><<<dim3(2, 2, 8), 256, 0, stream>>>(qbh, kbh, nullptr, nullptr, logalpha, 1024, 1024, 1024);

  gumbel_k<<<dim3(2048), 256, 0, stream>>>(logalpha, ebuf);
  sink_rc_k<<<dim3(8), 1024, 0, stream>>>(ebuf, attnw, wsh);

  gemm128<2><<<dim3(2048), 256, 0, stream>>>(wsh, vt, nullptr, nullptr, attnh, 256, 256, 256);
  gemm128<3><<<dim3(2048), 256, 0, stream>>>(attnh, woh, bo, nullptr, out, 1024, 1024, 1024);
}

// Round 18
// 352.837 us; speedup vs baseline: 1.1771x; 1.0710x over previous
//
#include <hip/hip_runtime.h>

// SinkhornAttention on MI355X — r17 pipeline + heterogeneous-block fusion:
//   sinkvt_k = sinkhorn (blocks 0-7) ∥ V-transpose (blocks 8+)  — recovers the
//   248 idle CUs during the 8-block sinkhorn (single stream = no overlap).
//   cb_k = weight-convert ∥ bucket-mean.
// All math byte-identical to r17 (377.9us, absmax 0.015625).
// T=S=4096, B=8, E=1024, BUCKET=16 -> nb=nkb=256. TAU=0.75, ITERS=8, SCALE=1/32.
// d_out = [ out | attn_weights | log_alpha ] f32.
// Noise (verified r7): threefry2x32 partitionable, counts (0,i), draw = o0 ^ o1.

typedef float    f32x4 __attribute__((ext_vector_type(4)));
typedef _Float16 h4    __attribute__((ext_vector_type(4)));
typedef _Float16 h8    __attribute__((ext_vector_type(8)));

#define OUT_ELEMS 33554432
#define AW_ELEMS  524288

__device__ __forceinline__ void gload16(const void* g, void* l) {
  __builtin_amdgcn_global_load_lds((__attribute__((address_space(1))) void*)g,
                                   (__attribute__((address_space(3))) void*)l,
                                   16, 0, 0);
}

// ---------------- fused: weight f32->f16 (blocks 0-3071) ∥ bucket mean -------
__global__ __launch_bounds__(256) void cb_k(const float* __restrict__ wq,
                                            const float* __restrict__ wk,
                                            const float* __restrict__ wo,
                                            _Float16* __restrict__ wdst,
                                            const float* __restrict__ q,
                                            const float* __restrict__ k,
                                            _Float16* __restrict__ qbar,
                                            _Float16* __restrict__ kbar) {
  int bid = blockIdx.x;
  if (bid < 3072) {
    int which = bid >> 10;
    const float* src = which == 0 ? wq : (which == 1 ? wk : wo);
    size_t idx = (size_t)(bid & 1023) * 256 + threadIdx.x;
    f32x4 v = ((const f32x4*)src)[idx];
    ((h4*)(wdst + (size_t)which * 1048576))[idx] = __builtin_convertvector(v, h4);
  } else {
    int vb = bid - 3072;                                          // 0..4095
    const float* src = (vb >= 2048) ? k : q;
    _Float16* dst = (vb >= 2048) ? kbar : qbar;
    unsigned t = (unsigned)(vb & 2047) * 256 + threadIdx.x;       // 0..524287
    int e4 = t & 255, i = (t >> 8) & 255, b = t >> 16;
    const f32x4* p = (const f32x4*)(src + ((size_t)(i * 16) * 8 + b) * 1024) + e4;
    f32x4 acc = {0.f, 0.f, 0.f, 0.f};
    #pragma unroll
    for (int j = 0; j < 16; ++j) acc += p[j * 2048];
    acc *= 0.0625f;
    ((h4*)(dst + (size_t)(b * 256 + i) * 1024))[e4] = __builtin_convertvector(acc, h4);
  }
}

// ---------------- JAX threefry2x32 gumbel (verified r7) ----------------------
__device__ __forceinline__ unsigned rotl32(unsigned x, int r) {
  return (x << r) | (x >> (32 - r));
}
__global__ __launch_bounds__(256) void gumbel_k(const float* __restrict__ logits,
                                                float* __restrict__ ebuf) {
  unsigned i = blockIdx.x * 256 + threadIdx.x;                    // 0..524287
  const unsigned k0 = 0u, k1 = 42u, k2 = 0u ^ 42u ^ 0x1BD11BDAu;
  unsigned x0 = 0u + k0, x1 = i + k1;                             // counts (hi,lo)=(0,i)
#define R4(a,b,c,d) \
  x0 += x1; x1 = rotl32(x1, a); x1 ^= x0; \
  x0 += x1; x1 = rotl32(x1, b); x1 ^= x0; \
  x0 += x1; x1 = rotl32(x1, c); x1 ^= x0; \
  x0 += x1; x1 = rotl32(x1, d); x1 ^= x0;
  R4(13,15,26,6)  x0 += k1; x1 += k2 + 1u;
  R4(17,29,16,24) x0 += k2; x1 += k0 + 2u;
  R4(13,15,26,6)  x0 += k0; x1 += k1 + 3u;
  R4(17,29,16,24) x0 += k1; x1 += k2 + 4u;
  R4(13,15,26,6)  x0 += k2; x1 += k0 + 5u;
#undef R4
  unsigned bits = x0 ^ x1;
  float u = __builtin_bit_cast(float, (bits >> 9) | 0x3f800000u) - 1.0f;
  float g = -logf(-logf(u + 1e-6f) + 1e-6f);
  ebuf[i] = __expf((logits[i] + g) / 0.75f);
}

// ---------------- fused: sinkhorn (blocks 0-7) ∥ V-transpose (blocks 8+) -----
// sink: scaling vectors a,b in LDS vs read-only exp-domain E (r15, verified).
// vtrans: vt[b][j][e][k] = v[(k*16+j)*8+b][e], 4 tiles per 1024-thr block.
__global__ __launch_bounds__(1024) void sinkvt_k(const float* __restrict__ ein,
                                                 float* __restrict__ attnw,
                                                 _Float16* __restrict__ wsh,
                                                 const float* __restrict__ v,
                                                 _Float16* __restrict__ vt) {
  __shared__ __attribute__((aligned(16))) char smem[36864];
  const int t = threadIdx.x;
  if (blockIdx.x < 8) {
    // ---------------- sinkhorn path (r15 body verbatim) ----------------------
    const int b = blockIdx.x;
    const int r = t >> 2, p = t & 3;       // row-sweep role
    const int k = t & 255, g = t >> 8;     // col-sweep role
    const float* Eb = ein + (size_t)b * 65536;
    const f32x4* Eb4 = (const f32x4*)Eb;
    float* ra = (float*)smem;                       // 256
    float* cb = ra + 256;                           // 256
    float (*part)[256] = (float (*)[256])(cb + 256);// 4x256
    if (t < 256) cb[t] = 1.0f;
    __syncthreads();
    const f32x4* cb4 = (const f32x4*)cb;

    for (int it = 0; it < 8; ++it) {
      float s = 0.f;
      #pragma unroll
      for (int i = 0; i < 16; ++i) {
        f32x4 e = Eb4[r * 64 + p * 16 + i];
        f32x4 c = cb4[p * 16 + i];
        f32x4 m = e * c;
        s += (m[0] + m[1]) + (m[2] + m[3]);
      }
      s += __shfl_xor(s, 1, 64);
      s += __shfl_xor(s, 2, 64);
      if (p == 0) ra[r] = 1.0f / s;
      __syncthreads();
      float s2 = 0.f;
      #pragma unroll 8
      for (int q2 = 0; q2 < 64; ++q2) {
        int row = g * 64 + q2;
        s2 += Eb[row * 256 + k] * ra[row];
      }
      part[g][k] = s2;
      __syncthreads();
      if (t < 256) {
        cb[t] = 1.0f / (part[0][t] + part[1][t] + part[2][t] + part[3][t]);
      }
      __syncthreads();
    }

    const float arow = ra[r];
    f32x4* aw = (f32x4*)(attnw + (size_t)b * 65536 + r * 256 + p * 64);
    h4* wh = (h4*)(wsh + (size_t)b * 65536 + r * 256 + p * 64);
    #pragma unroll
    for (int i = 0; i < 16; ++i) {
      f32x4 e = Eb4[r * 64 + p * 16 + i];
      f32x4 c = cb4[p * 16 + i];
      f32x4 w = e * c * arow;
      aw[i] = w;
      h4 hv;
      hv[0] = (_Float16)w[0]; hv[1] = (_Float16)w[1];
      hv[2] = (_Float16)w[2]; hv[3] = (_Float16)w[3];
      wh[i] = hv;
    }
  } else {
    // ---------------- vtrans path (r17 body, 4 tiles/block) ------------------
    const int s = t >> 8, t2 = t & 255;
    int bid = (blockIdx.x - 8) * 4 + s;              // 0..8191
    _Float16 (*tile)[72] = (_Float16 (*)[72])(smem + s * 9216);
    int kb = bid & 3, eb = (bid >> 2) & 15, j = (bid >> 6) & 15, b = bid >> 10;
    int k0 = kb * 64, e0 = eb * 64;
    int r = t2 >> 2, qq = t2 & 3;
    const float* src = v + ((size_t)((k0 + r) * 16 + j) * 8 + b) * 1024 + e0;
    #pragma unroll
    for (int ii = 0; ii < 4; ++ii) {
      f32x4 x = ((const f32x4*)src)[qq + ii * 4];
      *(h4*)&tile[r][(qq + ii * 4) * 4] = __builtin_convertvector(x, h4);
    }
    __syncthreads();
    _Float16* dstp = vt + (((size_t)(b * 16 + j) * 1024 + e0 + r) * 256 + k0 + qq * 16);
    h8 o0, o1;
    #pragma unroll
    for (int kk = 0; kk < 8; ++kk) o0[kk] = tile[qq * 16 + kk][r];
    #pragma unroll
    for (int kk = 0; kk < 8; ++kk) o1[kk] = tile[qq * 16 + 8 + kk][r];
    *(h8*)dstp = o0;
    *(h8*)(dstp + 8) = o1;
  }
}

// ---------------- generic 128x128 NT MFMA GEMM (m97 structure) ---------------
// C[M,N] = A[M,K] @ B[N,K]^T ; A,B f16 K-contiguous. 256 thr, 4 waves, BK=32.
// MODE 0: proj (grid 128 x 1 x 2, z = q/k) -> f16 out + bias (z-strided slabs)
// MODE 1: logits  (3-D grid)                   -> f32 /32 to log_alpha
// MODE 2: attn    (1-D grid 2048, XCD-chunked) -> f16 attnh
// MODE 3: outproj (1-D grid 2048, XCD-chunked) -> f32 out + bias
template <int MODE>
__global__ __launch_bounds__(256) void gemm128(const _Float16* __restrict__ A,
                                               const _Float16* __restrict__ B,
                                               const float* __restrict__ bias,
                                               const float* __restrict__ bias2,
                                               void* __restrict__ out0,
                                               int K, int lda, int ldb) {
  const int tid = threadIdx.x, lane = tid & 63, w = tid >> 6;
  int bx = blockIdx.x, by = blockIdx.y, bz = blockIdx.z;
  if constexpr (MODE == 0) {           // per-z grid 128: m=wid>>3 (16), n=wid&7
    int wid = ((bx & 7) << 4) + (bx >> 3);
    by = wid & 7; bx = wid >> 3;
  }
  if constexpr (MODE == 2) {           // grid 2048: x(2) fastest, y(8), z(128)
    int wid = ((bx & 7) << 8) + (bx >> 3);
    bz = wid >> 4; by = (wid >> 1) & 7; bx = wid & 1;
  }
  if constexpr (MODE == 3) {           // grid 2048: m=wid>>3 (256), n=wid&7
    int wid = ((bx & 7) << 8) + (bx >> 3);
    by = wid & 7; bx = wid >> 3;
  }
  const int m0 = bx * 128, n0 = by * 128;
  const _Float16* Ab = A;
  const _Float16* Bb = B;
  const float* bs = bias;
  if constexpr (MODE == 0) {
    Ab += (size_t)bz * 2097152;        // qbar -> kbar
    Bb += (size_t)bz * 1048576;        // wqh  -> wkh
    if (bz) bs = bias2;                // bq   -> bk
  }
  if constexpr (MODE == 1) { Ab += (size_t)bz * 262144; Bb += (size_t)bz * 262144; }
  if constexpr (MODE == 2) { Ab += (size_t)(bz >> 4) * 65536; Bb += (size_t)bz * 262144; }
  __shared__ _Float16 lA[128 * 32];
  __shared__ _Float16 lB[128 * 32];
  f32x4 acc[4][4] = {};
  const int wm = (w >> 1) * 64, wn = (w & 1) * 64;
  const int fr = lane & 15, fk = (lane >> 4) * 8;
  const int q0 = tid, q1 = tid + 256;

  for (int kt = 0; kt < K; kt += 32) {
    __syncthreads();
    gload16(Ab + (size_t)(m0 + (q0 >> 2)) * lda + kt + (q0 & 3) * 8, &lA[(w * 64) * 8]);
    gload16(Ab + (size_t)(m0 + (q1 >> 2)) * lda + kt + (q1 & 3) * 8, &lA[(256 + w * 64) * 8]);
    gload16(Bb + (size_t)(n0 + (q0 >> 2)) * ldb + kt + (q0 & 3) * 8, &lB[(w * 64) * 8]);
    gload16(Bb + (size_t)(n0 + (q1 >> 2)) * ldb + kt + (q1 & 3) * 8, &lB[(256 + w * 64) * 8]);
    __syncthreads();
    h8 af[4], bf[4];
    #pragma unroll
    for (int i = 0; i < 4; ++i) {
      af[i] = *(const h8*)&lA[(wm + i * 16 + fr) * 32 + fk];
      bf[i] = *(const h8*)&lB[(wn + i * 16 + fr) * 32 + fk];
    }
    #pragma unroll
    for (int mi = 0; mi < 4; ++mi)
      #pragma unroll
      for (int ni = 0; ni < 4; ++ni)
        acc[mi][ni] = __builtin_amdgcn_mfma_f32_16x16x32_f16(af[mi], bf[ni], acc[mi][ni], 0, 0, 0);
  }

  const int er = (lane >> 4) * 4;
  #pragma unroll
  for (int mi = 0; mi < 4; ++mi) {
    #pragma unroll
    for (int ni = 0; ni < 4; ++ni) {
      #pragma unroll
      for (int r = 0; r < 4; ++r) {
        int row = m0 + wm + mi * 16 + er + r;
        int col = n0 + wn + ni * 16 + fr;
        float val = acc[mi][ni][r];
        if constexpr (MODE == 0) {
          ((_Float16*)out0)[(size_t)bz * 2097152 + (size_t)row * 1024 + col] =
              (_Float16)(val + bs[col]);
        } else if constexpr (MODE == 1) {
          ((float*)out0)[(size_t)bz * 65536 + row * 256 + col] = val * 0.03125f;
        } else if constexpr (MODE == 2) {
          int b = bz >> 4, j = bz & 15;
          ((_Float16*)out0)[((size_t)(b * 4096 + row * 16 + j)) * 1024 + col] = (_Float16)val;
        } else {
          int bb = row >> 12, t = row & 4095;
          ((float*)out0)[((size_t)t * 8 + bb) * 1024 + col] = val + bs[col];
        }
      }
    }
  }
}

// -----------------------------------------------------------------------------
extern "C" void kernel_launch(void* const* d_in, const int* in_sizes, int n_in,
                              void* d_out, int out_size, void* d_ws, size_t ws_size,
                              hipStream_t stream) {
  const float* query = (const float*)d_in[0];
  const float* key   = (const float*)d_in[1];
  const float* value = (const float*)d_in[2];
  const float* wq    = (const float*)d_in[3];
  const float* bq    = (const float*)d_in[4];
  const float* wk    = (const float*)d_in[5];
  const float* bk    = (const float*)d_in[6];
  const float* wo    = (const float*)d_in[7];
  const float* bo    = (const float*)d_in[8];

  float* out      = (float*)d_out;
  float* attnw    = out + OUT_ELEMS;            // 8*256*256
  float* logalpha = out + OUT_ELEMS + AW_ELEMS; // logits (pre-noise)

  char* ws = (char*)d_ws;
  const size_t MB = 1024 * 1024;
  _Float16* wqh   = (_Float16*)(ws + 0 * MB);   // 2 MB  (wkh at +2MB, woh at +4MB)
  _Float16* woh   = (_Float16*)(ws + 4 * MB);   // 2 MB
  _Float16* qbar  = (_Float16*)(ws + 6 * MB);   // 4 MB  (2048x1024; kbar at +4MB)
  _Float16* kbar  = (_Float16*)(ws + 10 * MB);  // 4 MB
  _Float16* qbh   = (_Float16*)(ws + 14 * MB);  // 4 MB  (kbh at +4MB)
  _Float16* kbh   = (_Float16*)(ws + 18 * MB);  // 4 MB
  float*    ebuf  = (float*)(ws + 22 * MB);     // 2 MB  exp-domain entries
  _Float16* wsh   = (_Float16*)(ws + 25 * MB);  // 1 MB  attn weights f16
  _Float16* vt    = (_Float16*)(ws + 26 * MB);  // 64 MB vt[b][j][e][k]
  _Float16* attnh = (_Float16*)(ws + 90 * MB);  // 64 MB attn (B,T,E) f16
  (void)in_sizes; (void)n_in; (void)out_size; (void)ws_size;

  cb_k<<<dim3(7168), 256, 0, stream>>>(wq, wk, wo, wqh, query, key, qbar, kbar);

  gemm128<0><<<dim3(128, 1, 2), 256, 0, stream>>>(qbar, wqh, bq, bk, qbh, 1024, 1024, 1024);
  gemm128<1><<<dim3(2, 2, 8), 256, 0, stream>>>(qbh, kbh, nullptr, nullptr, logalpha, 1024, 1024, 1024);

  gumbel_k<<<dim3(2048), 256, 0, stream>>>(logalpha, ebuf);
  sinkvt_k<<<dim3(2056), 1024, 0, stream>>>(ebuf, attnw, wsh, value, vt);

  gemm128<2><<<dim3(2048), 256, 0, stream>>>(wsh, vt, nullptr, nullptr, attnh, 256, 256, 256);
  gemm128<3><<<dim3(2048), 256, 0, stream>>>(attnh, woh, bo, nullptr, out, 1024, 1024, 1024);
}